// Round 1
// baseline (4022.993 us; speedup 1.0000x reference)
//
#include <hip/hip_runtime.h>
#include <math.h>

#define B 1024
#define D 512
#define KC 100000
#define MARGIN 0.3f
#define EPSSM 0.1f

// ---------------- init workspace ----------------
__global__ void init_ws(float* ws) {
    int i = blockIdx.x * blockDim.x + threadIdx.x;
    if (i < 2 * B) ws[i] = 0.f;   // sumexp[B], sumlogit[B]
}

// ---------------- triplet: batch-hard per 8 rows ----------------
__global__ __launch_bounds__(256) void triplet_kernel(const float* __restrict__ x,
                                                      const int* __restrict__ labels,
                                                      float* __restrict__ tw) {
    const int tid = threadIdx.x;
    const int row0 = blockIdx.x * 8;
    __shared__ float xs[8][D];
    __shared__ int labs[8];
    __shared__ float sqi[8];
    __shared__ float red_ap[8][4], red_an[8][4];

    for (int f = tid; f < 8 * (D / 4); f += 256) {
        int r = f / (D / 4);
        int p = f % (D / 4);
        *(float4*)&xs[r][p * 4] = *(const float4*)&x[(size_t)(row0 + r) * D + p * 4];
    }
    if (tid < 8) labs[tid] = labels[row0 + tid];
    __syncthreads();
    if (tid < 8) {
        float s = 0.f;
        for (int k = 0; k < D; ++k) s += xs[tid][k] * xs[tid][k];
        sqi[tid] = s;
    }
    __syncthreads();

    float ap[8], an[8];
#pragma unroll
    for (int r = 0; r < 8; ++r) { ap[r] = -INFINITY; an[r] = INFINITY; }

    for (int j = tid; j < B; j += 256) {
        int labj = labels[j];
        float dot[8];
        float sqj = 0.f;
#pragma unroll
        for (int r = 0; r < 8; ++r) dot[r] = 0.f;
        for (int kc = 0; kc < D; kc += 32) {
            float4 xj[8];
#pragma unroll
            for (int u = 0; u < 8; ++u) xj[u] = *(const float4*)&x[(size_t)j * D + kc + u * 4];
#pragma unroll
            for (int u = 0; u < 8; ++u)
                sqj += xj[u].x * xj[u].x + xj[u].y * xj[u].y + xj[u].z * xj[u].z + xj[u].w * xj[u].w;
#pragma unroll
            for (int r = 0; r < 8; ++r) {
                float d = 0.f;
#pragma unroll
                for (int u = 0; u < 8; ++u) {
                    const float4 a = *(const float4*)&xs[r][kc + u * 4];
                    d += a.x * xj[u].x + a.y * xj[u].y + a.z * xj[u].z + a.w * xj[u].w;
                }
                dot[r] += d;
            }
        }
#pragma unroll
        for (int r = 0; r < 8; ++r) {
            float d2 = sqi[r] + sqj - 2.f * dot[r];
            float dist = sqrtf(fmaxf(d2, 1e-12f));
            if (labj == labs[r]) ap[r] = fmaxf(ap[r], dist);
            else an[r] = fminf(an[r], dist);
        }
    }
#pragma unroll
    for (int r = 0; r < 8; ++r) {
        for (int o = 32; o >= 1; o >>= 1) {
            ap[r] = fmaxf(ap[r], __shfl_xor(ap[r], o));
            an[r] = fminf(an[r], __shfl_xor(an[r], o));
        }
    }
    int wid = tid >> 6;
    if ((tid & 63) == 0) {
#pragma unroll
        for (int r = 0; r < 8; ++r) { red_ap[r][wid] = ap[r]; red_an[r][wid] = an[r]; }
    }
    __syncthreads();
    if (tid < 8) {
        float a = -INFINITY, n = INFINITY;
#pragma unroll
        for (int w = 0; w < 4; ++w) { a = fmaxf(a, red_ap[tid][w]); n = fminf(n, red_an[tid][w]); }
        tw[row0 + tid] = fmaxf(a - n + MARGIN, 0.f);
    }
}

// ---------------- label logit: t[i] = x_i . W[label_i] + b[label_i] ----------------
__global__ __launch_bounds__(256) void tlabel_kernel(const float* __restrict__ x,
                                                     const float* __restrict__ W,
                                                     const float* __restrict__ bias,
                                                     const int* __restrict__ labels,
                                                     float* __restrict__ t) {
    int wid = threadIdx.x >> 6, lane = threadIdx.x & 63;
    int row = blockIdx.x * 4 + wid;
    int lab = labels[row];
    const float* xr = x + (size_t)row * D;
    const float* wr = W + (size_t)lab * D;
    float dsum = 0.f;
#pragma unroll
    for (int u = 0; u < 2; ++u) {
        int k = (lane * 2 + u) * 4;
        float4 a = *(const float4*)&xr[k];
        float4 w = *(const float4*)&wr[k];
        dsum += a.x * w.x + a.y * w.y + a.z * w.z + a.w * w.w;
    }
    for (int o = 32; o >= 1; o >>= 1) dsum += __shfl_xor(dsum, o);
    if (lane == 0) t[row] = dsum + bias[lab];
}

// ---------------- fused CE GEMM: per-row sum(exp(logit)) and sum(logit) ----------------
#define BM 128
#define BN 64
#define BK 32
#define LDT 36   // padded LDS leading dim (keeps 16B alignment, breaks bank aliasing)

__global__ __launch_bounds__(256) void ce_gemm(const float* __restrict__ x,
                                               const float* __restrict__ W,
                                               const float* __restrict__ bias,
                                               float* __restrict__ sumexp,
                                               float* __restrict__ sumlogit) {
    __shared__ float smem[BM * LDT + BN * LDT];
    float* As = smem;              // [BM][LDT]
    float* Bs = smem + BM * LDT;   // [BN][LDT]
    const int tid = threadIdx.x;
    const int tx = tid & 15, ty = tid >> 4;
    const int rowbase = blockIdx.x * BM;
    const int cbase = blockIdx.y * BN;

    float acc[8][4];
#pragma unroll
    for (int i = 0; i < 8; ++i)
#pragma unroll
        for (int j = 0; j < 4; ++j) acc[i][j] = 0.f;

    for (int kb = 0; kb < D; kb += BK) {
        __syncthreads();
        // stage A: BM x BK
        for (int f = tid; f < BM * BK / 4; f += 256) {
            int r = f >> 3, p = f & 7;
            *(float4*)&As[r * LDT + p * 4] = *(const float4*)&x[(size_t)(rowbase + r) * D + kb + p * 4];
        }
        // stage B (W rows): BN x BK, guarded for class tail
        for (int f = tid; f < BN * BK / 4; f += 256) {
            int r = f >> 3, p = f & 7;
            int c = cbase + r;
            float4 v = make_float4(0.f, 0.f, 0.f, 0.f);
            if (c < KC) v = *(const float4*)&W[(size_t)c * D + kb + p * 4];
            *(float4*)&Bs[r * LDT + p * 4] = v;
        }
        __syncthreads();
#pragma unroll
        for (int k4 = 0; k4 < BK / 4; ++k4) {
            float4 av[8], bv[4];
#pragma unroll
            for (int i = 0; i < 8; ++i) av[i] = *(const float4*)&As[(ty + 16 * i) * LDT + k4 * 4];
#pragma unroll
            for (int j = 0; j < 4; ++j) bv[j] = *(const float4*)&Bs[(tx + 16 * j) * LDT + k4 * 4];
#pragma unroll
            for (int i = 0; i < 8; ++i)
#pragma unroll
                for (int j = 0; j < 4; ++j)
                    acc[i][j] += av[i].x * bv[j].x + av[i].y * bv[j].y +
                                 av[i].z * bv[j].z + av[i].w * bv[j].w;
        }
    }

    // epilogue: per-row partial sum(exp) and sum(logit)
    float pexp[8], plog[8];
#pragma unroll
    for (int i = 0; i < 8; ++i) { pexp[i] = 0.f; plog[i] = 0.f; }
#pragma unroll
    for (int j = 0; j < 4; ++j) {
        int c = cbase + tx + 16 * j;
        if (c < KC) {
            float bb = bias[c];
#pragma unroll
            for (int i = 0; i < 8; ++i) {
                float lg = acc[i][j] + bb;
                pexp[i] += expf(lg);
                plog[i] += lg;
            }
        }
    }
    __syncthreads();
    float* redE = smem;             // [BM][16]
    float* redL = smem + BM * 16;   // [BM][16]
#pragma unroll
    for (int i = 0; i < 8; ++i) {
        int rl = ty + 16 * i;
        redE[rl * 16 + tx] = pexp[i];
        redL[rl * 16 + tx] = plog[i];
    }
    __syncthreads();
    if (tid < BM) {
        float se = 0.f, sl = 0.f;
#pragma unroll
        for (int u = 0; u < 16; ++u) { se += redE[tid * 16 + u]; sl += redL[tid * 16 + u]; }
        atomicAdd(&sumexp[rowbase + tid], se);
        atomicAdd(&sumlogit[rowbase + tid], sl);
    }
}

// ---------------- final combine ----------------
__global__ __launch_bounds__(1024) void final_kernel(const float* __restrict__ ws,
                                                     float* __restrict__ out) {
    const float* sumexp = ws;
    const float* sumlogit = ws + B;
    const float* t = ws + 2 * B;
    const float* tw = ws + 3 * B;
    int i = threadIdx.x;
    float lse = logf(sumexp[i]);
    float ce = lse - (1.f - EPSSM) * t[i] - (EPSSM / (float)KC) * sumlogit[i];
    float v = ce + tw[i];   // WEIGHT_T = WEIGHT_X = 1
    for (int o = 32; o >= 1; o >>= 1) v += __shfl_xor(v, o);
    __shared__ float red[16];
    int wid = threadIdx.x >> 6, lane = threadIdx.x & 63;
    if (lane == 0) red[wid] = v;
    __syncthreads();
    if (threadIdx.x == 0) {
        float s = 0.f;
#pragma unroll
        for (int w = 0; w < 16; ++w) s += red[w];
        out[0] = s / (float)B;
    }
}

extern "C" void kernel_launch(void* const* d_in, const int* in_sizes, int n_in,
                              void* d_out, int out_size, void* d_ws, size_t ws_size,
                              hipStream_t stream) {
    const float* x = (const float*)d_in[0];
    const float* W = (const float*)d_in[1];
    const float* bias = (const float*)d_in[2];
    const int* labels = (const int*)d_in[3];
    float* out = (float*)d_out;
    float* ws = (float*)d_ws;
    // ws layout (floats): [0,B)=sumexp  [B,2B)=sumlogit  [2B,3B)=t  [3B,4B)=triplet per-row

    init_ws<<<(2 * B + 255) / 256, 256, 0, stream>>>(ws);
    triplet_kernel<<<B / 8, 256, 0, stream>>>(x, labels, ws + 3 * B);
    tlabel_kernel<<<B / 4, 256, 0, stream>>>(x, W, bias, labels, ws + 2 * B);
    dim3 g(B / BM, (KC + BN - 1) / BN);
    ce_gemm<<<g, 256, 0, stream>>>(x, W, bias, ws, ws + B);
    final_kernel<<<1, 1024, 0, stream>>>(ws, out);
}

// Round 2
// 350.494 us; speedup vs baseline: 11.4781x; 11.4781x over previous
//
#include <hip/hip_runtime.h>
#include <math.h>

#define B 1024
#define D 512
#define KC 100000
#define MARGIN 0.3f
#define EPSSM 0.1f

typedef __attribute__((ext_vector_type(8))) short bf16x8;
typedef __attribute__((ext_vector_type(4))) float f32x4;

__device__ __forceinline__ unsigned short f2bf(float f) {
    union { float f; unsigned u; } v; v.f = f;
    unsigned r = v.u + 0x7FFFu + ((v.u >> 16) & 1u);
    return (unsigned short)(r >> 16);
}

// ---------------- init workspace ----------------
__global__ void init_ws(float* ws) {
    int i = blockIdx.x * blockDim.x + threadIdx.x;
    if (i < 2 * B) ws[i] = 0.f;   // sumexp[B], sumlogit[B]
}

// ---------------- triplet: batch-hard per 8 rows (fp32, small) ----------------
__global__ __launch_bounds__(256) void triplet_kernel(const float* __restrict__ x,
                                                      const int* __restrict__ labels,
                                                      float* __restrict__ tw) {
    const int tid = threadIdx.x;
    const int row0 = blockIdx.x * 8;
    __shared__ float xs[8][D];
    __shared__ int labs[8];
    __shared__ float sqi[8];
    __shared__ float red_ap[8][4], red_an[8][4];

    for (int f = tid; f < 8 * (D / 4); f += 256) {
        int r = f / (D / 4);
        int p = f % (D / 4);
        *(float4*)&xs[r][p * 4] = *(const float4*)&x[(size_t)(row0 + r) * D + p * 4];
    }
    if (tid < 8) labs[tid] = labels[row0 + tid];
    __syncthreads();
    if (tid < 8) {
        float s = 0.f;
        for (int k = 0; k < D; ++k) s += xs[tid][k] * xs[tid][k];
        sqi[tid] = s;
    }
    __syncthreads();

    float ap[8], an[8];
#pragma unroll
    for (int r = 0; r < 8; ++r) { ap[r] = -INFINITY; an[r] = INFINITY; }

    for (int j = tid; j < B; j += 256) {
        int labj = labels[j];
        float dot[8];
        float sqj = 0.f;
#pragma unroll
        for (int r = 0; r < 8; ++r) dot[r] = 0.f;
        for (int kc = 0; kc < D; kc += 32) {
            float4 xj[8];
#pragma unroll
            for (int u = 0; u < 8; ++u) xj[u] = *(const float4*)&x[(size_t)j * D + kc + u * 4];
#pragma unroll
            for (int u = 0; u < 8; ++u)
                sqj += xj[u].x * xj[u].x + xj[u].y * xj[u].y + xj[u].z * xj[u].z + xj[u].w * xj[u].w;
#pragma unroll
            for (int r = 0; r < 8; ++r) {
                float d = 0.f;
#pragma unroll
                for (int u = 0; u < 8; ++u) {
                    const float4 a = *(const float4*)&xs[r][kc + u * 4];
                    d += a.x * xj[u].x + a.y * xj[u].y + a.z * xj[u].z + a.w * xj[u].w;
                }
                dot[r] += d;
            }
        }
#pragma unroll
        for (int r = 0; r < 8; ++r) {
            float d2 = sqi[r] + sqj - 2.f * dot[r];
            float dist = sqrtf(fmaxf(d2, 1e-12f));
            if (labj == labs[r]) ap[r] = fmaxf(ap[r], dist);
            else an[r] = fminf(an[r], dist);
        }
    }
#pragma unroll
    for (int r = 0; r < 8; ++r) {
        for (int o = 32; o >= 1; o >>= 1) {
            ap[r] = fmaxf(ap[r], __shfl_xor(ap[r], o));
            an[r] = fminf(an[r], __shfl_xor(an[r], o));
        }
    }
    int wid = tid >> 6;
    if ((tid & 63) == 0) {
#pragma unroll
        for (int r = 0; r < 8; ++r) { red_ap[r][wid] = ap[r]; red_an[r][wid] = an[r]; }
    }
    __syncthreads();
    if (tid < 8) {
        float a = -INFINITY, n = INFINITY;
#pragma unroll
        for (int w = 0; w < 4; ++w) { a = fmaxf(a, red_ap[tid][w]); n = fminf(n, red_an[tid][w]); }
        tw[row0 + tid] = fmaxf(a - n + MARGIN, 0.f);
    }
}

// ---------------- label logit: t[i] = x_i . W[label_i] + b[label_i] ----------------
__global__ __launch_bounds__(256) void tlabel_kernel(const float* __restrict__ x,
                                                     const float* __restrict__ W,
                                                     const float* __restrict__ bias,
                                                     const int* __restrict__ labels,
                                                     float* __restrict__ t) {
    int wid = threadIdx.x >> 6, lane = threadIdx.x & 63;
    int row = blockIdx.x * 4 + wid;
    int lab = labels[row];
    const float* xr = x + (size_t)row * D;
    const float* wr = W + (size_t)lab * D;
    float dsum = 0.f;
#pragma unroll
    for (int u = 0; u < 2; ++u) {
        int k = (lane * 2 + u) * 4;
        float4 a = *(const float4*)&xr[k];
        float4 w = *(const float4*)&wr[k];
        dsum += a.x * w.x + a.y * w.y + a.z * w.z + a.w * w.w;
    }
    for (int o = 32; o >= 1; o >>= 1) dsum += __shfl_xor(dsum, o);
    if (lane == 0) t[row] = dsum + bias[lab];
}

// ---------------- fused CE GEMM (bf16 MFMA): per-row sum(exp(logit)), sum(logit) ----
// Tile 128x128, BK=64, 4 waves (2x2). Reg-staged fp32->bf16 with XOR-swizzled LDS.
#define BMg 128
#define BNg 128
#define BKg 64

__global__ __launch_bounds__(256) void ce_gemm_mfma(const float* __restrict__ x,
                                                    const float* __restrict__ W,
                                                    const float* __restrict__ bias,
                                                    float* __restrict__ sumexp,
                                                    float* __restrict__ sumlogit) {
    __shared__ float smemf[8192];                           // 32 KiB, dual-purpose
    unsigned short* As = (unsigned short*)smemf;            // [128][64] bf16
    unsigned short* Bs = ((unsigned short*)smemf) + 8192;   // [128][64] bf16

    const int tid = threadIdx.x;
    const int lane = tid & 63;
    const int wid = tid >> 6;
    const int wm = wid >> 1, wn = wid & 1;    // 2x2 wave grid
    const int q = lane >> 4;                  // quarter-wave 0..3
    const int l15 = lane & 15;

    const int rowbase = blockIdx.x * BMg;
    const int cbase = blockIdx.y * BNg;

    f32x4 acc[4][4];
#pragma unroll
    for (int i = 0; i < 4; ++i)
#pragma unroll
        for (int j = 0; j < 4; ++j) acc[i][j] = (f32x4){0.f, 0.f, 0.f, 0.f};

    // staging registers: 4 A-chunks + 4 B-chunks of 8 fp32 each
    float4 ra[4][2], rb[4][2];

#define LOADG(kb_)                                                                      \
    {                                                                                   \
        _Pragma("unroll")                                                               \
        for (int u = 0; u < 4; ++u) {                                                   \
            int ca = tid + 256 * u;                                                     \
            int r = ca >> 3, s = ca & 7;                                                \
            const float* pa = &x[(size_t)(rowbase + r) * D + (kb_) + s * 8];            \
            ra[u][0] = *(const float4*)pa;                                              \
            ra[u][1] = *(const float4*)(pa + 4);                                        \
            int c = cbase + r;                                                          \
            if (c < KC) {                                                               \
                const float* pb = &W[(size_t)c * D + (kb_) + s * 8];                    \
                rb[u][0] = *(const float4*)pb;                                          \
                rb[u][1] = *(const float4*)(pb + 4);                                    \
            } else {                                                                    \
                rb[u][0] = make_float4(0.f, 0.f, 0.f, 0.f);                             \
                rb[u][1] = make_float4(0.f, 0.f, 0.f, 0.f);                             \
            }                                                                           \
        }                                                                               \
    }

#define STORE_LDS()                                                                     \
    {                                                                                   \
        _Pragma("unroll")                                                               \
        for (int u = 0; u < 4; ++u) {                                                   \
            int ca = tid + 256 * u;                                                     \
            int r = ca >> 3, s = ca & 7;                                                \
            int ssw = s ^ (r & 7);                                                      \
            bf16x8 pv;                                                                  \
            pv[0] = (short)f2bf(ra[u][0].x); pv[1] = (short)f2bf(ra[u][0].y);           \
            pv[2] = (short)f2bf(ra[u][0].z); pv[3] = (short)f2bf(ra[u][0].w);           \
            pv[4] = (short)f2bf(ra[u][1].x); pv[5] = (short)f2bf(ra[u][1].y);           \
            pv[6] = (short)f2bf(ra[u][1].z); pv[7] = (short)f2bf(ra[u][1].w);           \
            *(bf16x8*)&As[r * 64 + ssw * 8] = pv;                                       \
            bf16x8 qv;                                                                  \
            qv[0] = (short)f2bf(rb[u][0].x); qv[1] = (short)f2bf(rb[u][0].y);           \
            qv[2] = (short)f2bf(rb[u][0].z); qv[3] = (short)f2bf(rb[u][0].w);           \
            qv[4] = (short)f2bf(rb[u][1].x); qv[5] = (short)f2bf(rb[u][1].y);           \
            qv[6] = (short)f2bf(rb[u][1].z); qv[7] = (short)f2bf(rb[u][1].w);           \
            *(bf16x8*)&Bs[r * 64 + ssw * 8] = qv;                                       \
        }                                                                               \
    }

    LOADG(0);
    for (int kb = 0; kb < D; kb += BKg) {
        __syncthreads();   // previous iteration's fragment reads done
        STORE_LDS();
        __syncthreads();
        if (kb + BKg < D) LOADG(kb + BKg);   // prefetch next tile, overlaps MFMA
#pragma unroll
        for (int ks = 0; ks < 2; ++ks) {
            bf16x8 af[4], bfr[4];
#pragma unroll
            for (int m = 0; m < 4; ++m) {
                int arow = wm * 64 + m * 16 + l15;
                int ssw = (ks * 4 + q) ^ (arow & 7);
                af[m] = *(bf16x8*)&As[arow * 64 + ssw * 8];
            }
#pragma unroll
            for (int n = 0; n < 4; ++n) {
                int brow = wn * 64 + n * 16 + l15;
                int ssw = (ks * 4 + q) ^ (brow & 7);
                bfr[n] = *(bf16x8*)&Bs[brow * 64 + ssw * 8];
            }
#pragma unroll
            for (int m = 0; m < 4; ++m)
#pragma unroll
                for (int n = 0; n < 4; ++n)
                    acc[m][n] = __builtin_amdgcn_mfma_f32_16x16x32_bf16(af[m], bfr[n], acc[m][n], 0, 0, 0);
        }
    }

    // ---- epilogue: per-row partial sum(exp) / sum(logit) ----
    __syncthreads();                 // all LDS frag reads complete; reuse smem
    float* redE = smemf;             // [128][32]
    float* redL = smemf + 4096;      // [128][32]

    float pexp[16], plog[16];
#pragma unroll
    for (int i = 0; i < 16; ++i) { pexp[i] = 0.f; plog[i] = 0.f; }

#pragma unroll
    for (int n = 0; n < 4; ++n) {
        int c = cbase + wn * 64 + n * 16 + l15;
        if (c < KC) {
            float bb = bias[c];
#pragma unroll
            for (int m = 0; m < 4; ++m)
#pragma unroll
                for (int r = 0; r < 4; ++r) {
                    float lg = acc[m][n][r] + bb;
                    pexp[m * 4 + r] += __expf(lg);
                    plog[m * 4 + r] += lg;
                }
        }
    }
#pragma unroll
    for (int m = 0; m < 4; ++m)
#pragma unroll
        for (int r = 0; r < 4; ++r) {
            int rl = wm * 64 + m * 16 + q * 4 + r;
            redE[rl * 32 + wn * 16 + l15] = pexp[m * 4 + r];
            redL[rl * 32 + wn * 16 + l15] = plog[m * 4 + r];
        }
    __syncthreads();
    if (tid < BMg) {
        float se = 0.f, sl = 0.f;
#pragma unroll
        for (int u = 0; u < 32; ++u) { se += redE[tid * 32 + u]; sl += redL[tid * 32 + u]; }
        atomicAdd(&sumexp[rowbase + tid], se);
        atomicAdd(&sumlogit[rowbase + tid], sl);
    }
#undef LOADG
#undef STORE_LDS
}

// ---------------- final combine ----------------
__global__ __launch_bounds__(1024) void final_kernel(const float* __restrict__ ws,
                                                     float* __restrict__ out) {
    const float* sumexp = ws;
    const float* sumlogit = ws + B;
    const float* t = ws + 2 * B;
    const float* tw = ws + 3 * B;
    int i = threadIdx.x;
    float lse = logf(sumexp[i]);
    float ce = lse - (1.f - EPSSM) * t[i] - (EPSSM / (float)KC) * sumlogit[i];
    float v = ce + tw[i];   // WEIGHT_T = WEIGHT_X = 1
    for (int o = 32; o >= 1; o >>= 1) v += __shfl_xor(v, o);
    __shared__ float red[16];
    int wid = threadIdx.x >> 6, lane = threadIdx.x & 63;
    if (lane == 0) red[wid] = v;
    __syncthreads();
    if (threadIdx.x == 0) {
        float s = 0.f;
#pragma unroll
        for (int w = 0; w < 16; ++w) s += red[w];
        out[0] = s / (float)B;
    }
}

extern "C" void kernel_launch(void* const* d_in, const int* in_sizes, int n_in,
                              void* d_out, int out_size, void* d_ws, size_t ws_size,
                              hipStream_t stream) {
    const float* x = (const float*)d_in[0];
    const float* W = (const float*)d_in[1];
    const float* bias = (const float*)d_in[2];
    const int* labels = (const int*)d_in[3];
    float* out = (float*)d_out;
    float* ws = (float*)d_ws;
    // ws layout (floats): [0,B)=sumexp  [B,2B)=sumlogit  [2B,3B)=t  [3B,4B)=triplet per-row

    init_ws<<<(2 * B + 255) / 256, 256, 0, stream>>>(ws);
    triplet_kernel<<<B / 8, 256, 0, stream>>>(x, labels, ws + 3 * B);
    tlabel_kernel<<<B / 4, 256, 0, stream>>>(x, W, bias, labels, ws + 2 * B);
    dim3 g(B / BMg, (KC + BNg - 1) / BNg);
    ce_gemm_mfma<<<g, 256, 0, stream>>>(x, W, bias, ws, ws + B);
    final_kernel<<<1, 1024, 0, stream>>>(ws, out);
}

// Round 3
// 281.493 us; speedup vs baseline: 14.2917x; 1.2451x over previous
//
#include <hip/hip_runtime.h>
#include <hip/hip_bf16.h>
#include <math.h>

#define B 1024
#define D 512
#define KC 100000
#define MARGIN 0.3f
#define EPSSM 0.1f

typedef __attribute__((ext_vector_type(8))) short bf16x8;
typedef __attribute__((ext_vector_type(4))) float f32x4;

__device__ __forceinline__ unsigned cvtpk(float lo, float hi) {
    union { __hip_bfloat162 h2; unsigned u; } cv;
    cv.h2 = __float22bfloat162_rn(make_float2(lo, hi));
    return cv.u;
}

// ---------------- init workspace ----------------
__global__ void init_ws(float* ws) {
    int i = blockIdx.x * blockDim.x + threadIdx.x;
    if (i < 2 * B) ws[i] = 0.f;   // sumexp[B], sumlogit[B]
}

// ---------------- triplet: batch-hard per 8 rows (fp32, small) ----------------
__global__ __launch_bounds__(256) void triplet_kernel(const float* __restrict__ x,
                                                      const int* __restrict__ labels,
                                                      float* __restrict__ tw) {
    const int tid = threadIdx.x;
    const int row0 = blockIdx.x * 8;
    __shared__ float xs[8][D];
    __shared__ int labs[8];
    __shared__ float sqi[8];
    __shared__ float red_ap[8][4], red_an[8][4];

    for (int f = tid; f < 8 * (D / 4); f += 256) {
        int r = f / (D / 4);
        int p = f % (D / 4);
        *(float4*)&xs[r][p * 4] = *(const float4*)&x[(size_t)(row0 + r) * D + p * 4];
    }
    if (tid < 8) labs[tid] = labels[row0 + tid];
    __syncthreads();
    if (tid < 8) {
        float s = 0.f;
        for (int k = 0; k < D; ++k) s += xs[tid][k] * xs[tid][k];
        sqi[tid] = s;
    }
    __syncthreads();

    float ap[8], an[8];
#pragma unroll
    for (int r = 0; r < 8; ++r) { ap[r] = -INFINITY; an[r] = INFINITY; }

    for (int j = tid; j < B; j += 256) {
        int labj = labels[j];
        float dot[8];
        float sqj = 0.f;
#pragma unroll
        for (int r = 0; r < 8; ++r) dot[r] = 0.f;
        for (int kc = 0; kc < D; kc += 32) {
            float4 xj[8];
#pragma unroll
            for (int u = 0; u < 8; ++u) xj[u] = *(const float4*)&x[(size_t)j * D + kc + u * 4];
#pragma unroll
            for (int u = 0; u < 8; ++u)
                sqj += xj[u].x * xj[u].x + xj[u].y * xj[u].y + xj[u].z * xj[u].z + xj[u].w * xj[u].w;
#pragma unroll
            for (int r = 0; r < 8; ++r) {
                float d = 0.f;
#pragma unroll
                for (int u = 0; u < 8; ++u) {
                    const float4 a = *(const float4*)&xs[r][kc + u * 4];
                    d += a.x * xj[u].x + a.y * xj[u].y + a.z * xj[u].z + a.w * xj[u].w;
                }
                dot[r] += d;
            }
        }
#pragma unroll
        for (int r = 0; r < 8; ++r) {
            float d2 = sqi[r] + sqj - 2.f * dot[r];
            float dist = sqrtf(fmaxf(d2, 1e-12f));
            if (labj == labs[r]) ap[r] = fmaxf(ap[r], dist);
            else an[r] = fminf(an[r], dist);
        }
    }
#pragma unroll
    for (int r = 0; r < 8; ++r) {
        for (int o = 32; o >= 1; o >>= 1) {
            ap[r] = fmaxf(ap[r], __shfl_xor(ap[r], o));
            an[r] = fminf(an[r], __shfl_xor(an[r], o));
        }
    }
    int wid = tid >> 6;
    if ((tid & 63) == 0) {
#pragma unroll
        for (int r = 0; r < 8; ++r) { red_ap[r][wid] = ap[r]; red_an[r][wid] = an[r]; }
    }
    __syncthreads();
    if (tid < 8) {
        float a = -INFINITY, n = INFINITY;
#pragma unroll
        for (int w = 0; w < 4; ++w) { a = fmaxf(a, red_ap[tid][w]); n = fminf(n, red_an[tid][w]); }
        tw[row0 + tid] = fmaxf(a - n + MARGIN, 0.f);
    }
}

// ---------------- label logit: t[i] = x_i . W[label_i] + b[label_i] ----------------
__global__ __launch_bounds__(256) void tlabel_kernel(const float* __restrict__ x,
                                                     const float* __restrict__ W,
                                                     const float* __restrict__ bias,
                                                     const int* __restrict__ labels,
                                                     float* __restrict__ t) {
    int wid = threadIdx.x >> 6, lane = threadIdx.x & 63;
    int row = blockIdx.x * 4 + wid;
    int lab = labels[row];
    const float* xr = x + (size_t)row * D;
    const float* wr = W + (size_t)lab * D;
    float dsum = 0.f;
#pragma unroll
    for (int u = 0; u < 2; ++u) {
        int k = (lane * 2 + u) * 4;
        float4 a = *(const float4*)&xr[k];
        float4 w = *(const float4*)&wr[k];
        dsum += a.x * w.x + a.y * w.y + a.z * w.z + a.w * w.w;
    }
    for (int o = 32; o >= 1; o >>= 1) dsum += __shfl_xor(dsum, o);
    if (lane == 0) t[row] = dsum + bias[lab];
}

// ---------------- fused CE GEMM (bf16 MFMA): per-row sum(exp(logit)), sum(logit) ----
// Tile 128x128, BK=64, 4 waves (2x2). Reg-staged fp32->bf16 (packed cvt) with
// XOR-swizzled LDS. 1D grid with XCD-aware mapping: the 8 row-blocks sharing a
// W column-panel land on the SAME XCD so its private L2 serves W once.
#define BMg 128
#define BNg 128
#define BKg 64
#define NCOLB 782            // ceil(KC/BNg)
#define NCOLB_PAD 784        // padded to multiple of 8

__global__ __launch_bounds__(256) void ce_gemm_mfma(const float* __restrict__ x,
                                                    const float* __restrict__ W,
                                                    const float* __restrict__ bias,
                                                    float* __restrict__ sumexp,
                                                    float* __restrict__ sumlogit) {
    // XCD-aware decode: hw id b -> xcd = b&7 (round-robin dispatch), slot = b>>3.
    // 8 consecutive slots on one XCD = the 8 row-blocks of one column panel.
    {
    }
    const int b = blockIdx.x;
    const int xcd = b & 7;
    const int slot = b >> 3;
    const int c = ((slot >> 3) << 3) | xcd;   // column-panel index
    const int r = slot & 7;                   // row-panel index
    if (c >= NCOLB) return;

    __shared__ float smemf[8192];                           // 32 KiB, dual-purpose
    unsigned short* As = (unsigned short*)smemf;            // [128][64] bf16
    unsigned short* Bs = ((unsigned short*)smemf) + 8192;   // [128][64] bf16

    const int tid = threadIdx.x;
    const int lane = tid & 63;
    const int wid = tid >> 6;
    const int wm = wid >> 1, wn = wid & 1;    // 2x2 wave grid
    const int q = lane >> 4;                  // quarter-wave 0..3
    const int l15 = lane & 15;

    const int rowbase = r * BMg;
    const int cbase = c * BNg;

    f32x4 acc[4][4];
#pragma unroll
    for (int i = 0; i < 4; ++i)
#pragma unroll
        for (int j = 0; j < 4; ++j) acc[i][j] = (f32x4){0.f, 0.f, 0.f, 0.f};

    // staging registers: 4 A-chunks + 4 B-chunks of 8 fp32 each
    float4 ra[4][2], rb[4][2];

#define LOADG(kb_)                                                                      \
    {                                                                                   \
        _Pragma("unroll")                                                               \
        for (int u = 0; u < 4; ++u) {                                                   \
            int ca = tid + 256 * u;                                                     \
            int rr = ca >> 3, s = ca & 7;                                               \
            const float* pa = &x[(size_t)(rowbase + rr) * D + (kb_) + s * 8];           \
            ra[u][0] = *(const float4*)pa;                                              \
            ra[u][1] = *(const float4*)(pa + 4);                                        \
            int cc = cbase + rr;                                                        \
            if (cc < KC) {                                                              \
                const float* pb = &W[(size_t)cc * D + (kb_) + s * 8];                   \
                rb[u][0] = *(const float4*)pb;                                          \
                rb[u][1] = *(const float4*)(pb + 4);                                    \
            } else {                                                                    \
                rb[u][0] = make_float4(0.f, 0.f, 0.f, 0.f);                             \
                rb[u][1] = make_float4(0.f, 0.f, 0.f, 0.f);                             \
            }                                                                           \
        }                                                                               \
    }

#define STORE_LDS()                                                                     \
    {                                                                                   \
        _Pragma("unroll")                                                               \
        for (int u = 0; u < 4; ++u) {                                                   \
            int ca = tid + 256 * u;                                                     \
            int rr = ca >> 3, s = ca & 7;                                               \
            int ssw = s ^ (rr & 7);                                                     \
            unsigned pv[4];                                                             \
            pv[0] = cvtpk(ra[u][0].x, ra[u][0].y);                                      \
            pv[1] = cvtpk(ra[u][0].z, ra[u][0].w);                                      \
            pv[2] = cvtpk(ra[u][1].x, ra[u][1].y);                                      \
            pv[3] = cvtpk(ra[u][1].z, ra[u][1].w);                                      \
            *(uint4*)&As[rr * 64 + ssw * 8] = *(uint4*)pv;                              \
            unsigned qv[4];                                                             \
            qv[0] = cvtpk(rb[u][0].x, rb[u][0].y);                                      \
            qv[1] = cvtpk(rb[u][0].z, rb[u][0].w);                                      \
            qv[2] = cvtpk(rb[u][1].x, rb[u][1].y);                                      \
            qv[3] = cvtpk(rb[u][1].z, rb[u][1].w);                                      \
            *(uint4*)&Bs[rr * 64 + ssw * 8] = *(uint4*)qv;                              \
        }                                                                               \
    }

    LOADG(0);
    for (int kb = 0; kb < D; kb += BKg) {
        __syncthreads();   // previous iteration's fragment reads done
        STORE_LDS();
        __syncthreads();
        if (kb + BKg < D) LOADG(kb + BKg);   // prefetch next tile, overlaps MFMA
#pragma unroll
        for (int ks = 0; ks < 2; ++ks) {
            bf16x8 af[4], bfr[4];
#pragma unroll
            for (int m = 0; m < 4; ++m) {
                int arow = wm * 64 + m * 16 + l15;
                int ssw = (ks * 4 + q) ^ (arow & 7);
                af[m] = *(bf16x8*)&As[arow * 64 + ssw * 8];
            }
#pragma unroll
            for (int n = 0; n < 4; ++n) {
                int brow = wn * 64 + n * 16 + l15;
                int ssw = (ks * 4 + q) ^ (brow & 7);
                bfr[n] = *(bf16x8*)&Bs[brow * 64 + ssw * 8];
            }
#pragma unroll
            for (int m = 0; m < 4; ++m)
#pragma unroll
                for (int n = 0; n < 4; ++n)
                    acc[m][n] = __builtin_amdgcn_mfma_f32_16x16x32_bf16(af[m], bfr[n], acc[m][n], 0, 0, 0);
        }
    }

    // ---- epilogue: per-row partial sum(exp) / sum(logit) ----
    __syncthreads();                 // all LDS frag reads complete; reuse smem
    float* redE = smemf;             // [128][32]
    float* redL = smemf + 4096;      // [128][32]

    float pexp[16], plog[16];
#pragma unroll
    for (int i = 0; i < 16; ++i) { pexp[i] = 0.f; plog[i] = 0.f; }

#pragma unroll
    for (int n = 0; n < 4; ++n) {
        int cc = cbase + wn * 64 + n * 16 + l15;
        if (cc < KC) {
            float bb = bias[cc];
#pragma unroll
            for (int m = 0; m < 4; ++m)
#pragma unroll
                for (int rr = 0; rr < 4; ++rr) {
                    float lg = acc[m][n][rr] + bb;
                    pexp[m * 4 + rr] += __expf(lg);
                    plog[m * 4 + rr] += lg;
                }
        }
    }
#pragma unroll
    for (int m = 0; m < 4; ++m)
#pragma unroll
        for (int rr = 0; rr < 4; ++rr) {
            int rl = wm * 64 + m * 16 + q * 4 + rr;
            redE[rl * 32 + wn * 16 + l15] = pexp[m * 4 + rr];
            redL[rl * 32 + wn * 16 + l15] = plog[m * 4 + rr];
        }
    __syncthreads();
    if (tid < BMg) {
        float se = 0.f, sl = 0.f;
#pragma unroll
        for (int u = 0; u < 32; ++u) { se += redE[tid * 32 + u]; sl += redL[tid * 32 + u]; }
        atomicAdd(&sumexp[rowbase + tid], se);
        atomicAdd(&sumlogit[rowbase + tid], sl);
    }
#undef LOADG
#undef STORE_LDS
}

// ---------------- final combine ----------------
__global__ __launch_bounds__(1024) void final_kernel(const float* __restrict__ ws,
                                                     float* __restrict__ out) {
    const float* sumexp = ws;
    const float* sumlogit = ws + B;
    const float* t = ws + 2 * B;
    const float* tw = ws + 3 * B;
    int i = threadIdx.x;
    float lse = logf(sumexp[i]);
    float ce = lse - (1.f - EPSSM) * t[i] - (EPSSM / (float)KC) * sumlogit[i];
    float v = ce + tw[i];   // WEIGHT_T = WEIGHT_X = 1
    for (int o = 32; o >= 1; o >>= 1) v += __shfl_xor(v, o);
    __shared__ float red[16];
    int wid = threadIdx.x >> 6, lane = threadIdx.x & 63;
    if (lane == 0) red[wid] = v;
    __syncthreads();
    if (threadIdx.x == 0) {
        float s = 0.f;
#pragma unroll
        for (int w = 0; w < 16; ++w) s += red[w];
        out[0] = s / (float)B;
    }
}

extern "C" void kernel_launch(void* const* d_in, const int* in_sizes, int n_in,
                              void* d_out, int out_size, void* d_ws, size_t ws_size,
                              hipStream_t stream) {
    const float* x = (const float*)d_in[0];
    const float* W = (const float*)d_in[1];
    const float* bias = (const float*)d_in[2];
    const int* labels = (const int*)d_in[3];
    float* out = (float*)d_out;
    float* ws = (float*)d_ws;
    // ws layout (floats): [0,B)=sumexp  [B,2B)=sumlogit  [2B,3B)=t  [3B,4B)=triplet per-row

    init_ws<<<(2 * B + 255) / 256, 256, 0, stream>>>(ws);
    triplet_kernel<<<B / 8, 256, 0, stream>>>(x, labels, ws + 3 * B);
    tlabel_kernel<<<B / 4, 256, 0, stream>>>(x, W, bias, labels, ws + 2 * B);
    ce_gemm_mfma<<<8 * NCOLB_PAD, 256, 0, stream>>>(x, W, bias, ws, ws + B);
    final_kernel<<<1, 1024, 0, stream>>>(ws, out);
}